// Round 6
// baseline (255.144 us; speedup 1.0000x reference)
//
#include <hip/hip_runtime.h>
#include <math.h>

#define NNODES 50000
#define NEDGES 800000
#define INFEAT 256
#define OUTF   128
#define NEG_SLOPE 0.2f

// ---------------- zero ----------------
__global__ void kzero(int* p, int n) {
    int i = blockIdx.x * 256 + threadIdx.x;
    if (i < n) p[i] = 0;
}

// ---------------- degrees ----------------
__global__ void kdegrees(const int* __restrict__ src, const int* __restrict__ dst,
                         int* __restrict__ cnt_out, int* __restrict__ cnt_in, int E) {
    int i = blockIdx.x * 256 + threadIdx.x;
    if (i < E) {
        atomicAdd(&cnt_out[src[i]], 1);
        atomicAdd(&cnt_in[dst[i]], 1);
    }
}

// ---------------- scan, 2 kernels ----------------
__global__ void kblocksum(const int* __restrict__ cnt, int* __restrict__ bsums, int n) {
    __shared__ int red[16];
    int tid = threadIdx.x;
    int i = blockIdx.x * 1024 + tid;
    int v = (i < n) ? cnt[i] : 0;
    #pragma unroll
    for (int m = 1; m < 64; m <<= 1) v += __shfl_xor(v, m, 64);
    if ((tid & 63) == 0) red[tid >> 6] = v;
    __syncthreads();
    if (tid < 16) {
        int t = red[tid];
        #pragma unroll
        for (int m = 1; m < 16; m <<= 1) t += __shfl_xor(t, m, 64);
        if (tid == 0) bsums[blockIdx.x] = t;
    }
}

__global__ void kscanfull(const int* __restrict__ cnt, const int* __restrict__ bsums,
                          int* __restrict__ out, int n, int nb) {
    __shared__ int tmp[1024];
    __shared__ int base_s;
    int tid = threadIdx.x;
    int b = blockIdx.x;
    int i = b * 1024 + tid;
    if (tid == 0) {
        int run = 0;
        for (int bb = 0; bb < b; bb++) run += bsums[bb];
        base_s = run;
        if (b == nb - 1) out[n] = run + bsums[b];
    }
    int v = (i < n) ? cnt[i] : 0;
    tmp[tid] = v;
    __syncthreads();
    for (int off = 1; off < 1024; off <<= 1) {
        int t = (tid >= off) ? tmp[tid - off] : 0;
        __syncthreads();
        tmp[tid] += t;
        __syncthreads();
    }
    if (i < n) out[i] = tmp[tid] - v + base_s;
}

// ---------------- bucket edges by dst ----------------
__global__ void kbucket(const int* __restrict__ dst, const int* __restrict__ offs,
                        int* __restrict__ fill, int* __restrict__ ebd, int E) {
    int i = blockIdx.x * 256 + threadIdx.x;
    if (i < E) {
        int d = dst[i];
        int p = atomicAdd(&fill[d], 1);
        ebd[offs[d] + p] = i;
    }
}

// ---------------- GEMM: h = rsqrt(max(out_deg,1)) * (feat @ W) ----------------
#define BM 64
#define BK 32
__launch_bounds__(256)
__global__ void kgemm(const float* __restrict__ feat, const float* __restrict__ W,
                      const int* __restrict__ cnt_out, float* __restrict__ h, int M) {
    __shared__ float As[BK][68];
    __shared__ float Bs[BK][128];
    int tid = threadIdx.x;
    int tr = tid >> 4;
    int tc = tid & 15;
    int m0 = blockIdx.x * BM;
    float acc[4][8] = {};

    for (int kt = 0; kt < INFEAT; kt += BK) {
        #pragma unroll
        for (int r = 0; r < 2; r++) {
            int fi = tid * 2 + r;
            int row = fi >> 3;
            int kq  = fi & 7;
            int gr = m0 + row;
            float4 v = make_float4(0.f, 0.f, 0.f, 0.f);
            if (gr < M) v = *(const float4*)&feat[(size_t)gr * INFEAT + kt + kq * 4];
            As[kq * 4 + 0][row] = v.x;
            As[kq * 4 + 1][row] = v.y;
            As[kq * 4 + 2][row] = v.z;
            As[kq * 4 + 3][row] = v.w;
        }
        #pragma unroll
        for (int r = 0; r < 4; r++) {
            int fi = tid + 256 * r;
            int row = fi >> 5;
            int c4  = fi & 31;
            float4 v = *(const float4*)&W[(size_t)(kt + row) * OUTF + c4 * 4];
            *(float4*)&Bs[row][c4 * 4] = v;
        }
        __syncthreads();
        #pragma unroll
        for (int kk = 0; kk < BK; kk++) {
            float4 a  = *(const float4*)&As[kk][tr * 4];
            float4 b0 = *(const float4*)&Bs[kk][tc * 4];
            float4 b1 = *(const float4*)&Bs[kk][64 + tc * 4];
            float av[4] = {a.x, a.y, a.z, a.w};
            float bv[8] = {b0.x, b0.y, b0.z, b0.w, b1.x, b1.y, b1.z, b1.w};
            #pragma unroll
            for (int i = 0; i < 4; i++)
                #pragma unroll
                for (int j = 0; j < 8; j++)
                    acc[i][j] += av[i] * bv[j];
        }
        __syncthreads();
    }
    #pragma unroll
    for (int i = 0; i < 4; i++) {
        int gr = m0 + tr * 4 + i;
        if (gr < M) {
            int c = cnt_out[gr];
            float sc = rsqrtf((float)(c < 1 ? 1 : c));
            float4 o0 = make_float4(acc[i][0] * sc, acc[i][1] * sc, acc[i][2] * sc, acc[i][3] * sc);
            float4 o1 = make_float4(acc[i][4] * sc, acc[i][5] * sc, acc[i][6] * sc, acc[i][7] * sc);
            *(float4*)&h[(size_t)gr * OUTF + tc * 4] = o0;
            *(float4*)&h[(size_t)gr * OUTF + 64 + tc * 4] = o1;
        }
    }
}

// ---------------- per-dst aggregation: softmax + scatter-sum ----------------
// one wave per dst node. 8 groups of 8 lanes process 8 edges concurrently;
// lane (g,t): g=lane>>3, t=lane&7 owns feature cols t*16..t*16+15.
// Dot reduce = 3 shfl steps in-group. Lane l=g*8+t holds edge m=8*t+g for
// the softmax. All __shfl ops run with the FULL wave active.
__launch_bounds__(256)
__global__ void kaggregate(const float* __restrict__ h, const int* __restrict__ src,
                           const int* __restrict__ ebd, const int* __restrict__ offs,
                           const int* __restrict__ cnt_in, const float* __restrict__ bias,
                           float* __restrict__ e_tmp, float* __restrict__ out_rst,
                           float* __restrict__ out_es, int nnodes) {
    int wid = threadIdx.x >> 6;
    int lane = threadIdx.x & 63;
    int n = blockIdx.x * 4 + wid;
    if (n >= nnodes) return;

    int off = offs[n];
    int deg = cnt_in[n];

    if (deg <= 64) {
        int g = lane >> 3;          // group 0..7
        int t = lane & 7;           // sublane 0..7
        int c = t * 16;             // 16 cols per lane

        // tanh(h[dst]) for owned cols
        float4 th[4];
        #pragma unroll
        for (int q = 0; q < 4; q++) {
            float4 v = *(const float4*)&h[(size_t)n * OUTF + c + q * 4];
            th[q] = make_float4(tanhf(v.x), tanhf(v.y), tanhf(v.z), tanhf(v.w));
        }

        int eid = 0, s = 0;
        if (lane < deg) { eid = ebd[off + lane]; s = src[eid]; }

        float4 acc[4];
        #pragma unroll
        for (int q = 0; q < 4; q++) acc[q] = make_float4(0.f, 0.f, 0.f, 0.f);
        float myv = -INFINITY;      // e value of edge m = 8*t + g

        for (int base = 0; base < deg; base += 8) {
            int m = base + g;                   // m <= 63 (base <= 56, g <= 7)
            int sj = __shfl(s, m, 64);          // full wave active
            float4 hs[4];
            #pragma unroll
            for (int q = 0; q < 4; q++) hs[q] = make_float4(0.f, 0.f, 0.f, 0.f);
            if (m < deg) {
                const float* row = &h[(size_t)sj * OUTF + c];
                #pragma unroll
                for (int q = 0; q < 4; q++) hs[q] = *(const float4*)&row[q * 4];
            }
            float p = 0.f;
            #pragma unroll
            for (int q = 0; q < 4; q++) {
                acc[q].x += hs[q].x; acc[q].y += hs[q].y;
                acc[q].z += hs[q].z; acc[q].w += hs[q].w;
                p += hs[q].x * th[q].x + hs[q].y * th[q].y
                   + hs[q].z * th[q].z + hs[q].w * th[q].w;
            }
            #pragma unroll
            for (int msk = 1; msk < 8; msk <<= 1) p += __shfl_xor(p, msk, 64);
            float e = p > 0.f ? p : NEG_SLOPE * p;
            if (m < deg && t == (base >> 3)) myv = e;
        }

        if (deg > 0) {
            float mx = myv;
            #pragma unroll
            for (int msk = 1; msk < 64; msk <<= 1) mx = fmaxf(mx, __shfl_xor(mx, msk, 64));
            int m = 8 * t + g;      // the edge this lane holds
            float v = (m < deg) ? expf(myv - mx) : 0.f;
            float sum = v;
            #pragma unroll
            for (int msk = 1; msk < 64; msk <<= 1) sum += __shfl_xor(sum, msk, 64);
            float inv = 1.f / sum;
            int eidm = __shfl(eid, m, 64);      // full wave active
            if (m < deg) out_es[eidm] = v * inv;
        }

        // combine acc across the 8 groups (g bits are lane bits 3..5)
        #pragma unroll
        for (int msk = 8; msk < 64; msk <<= 1) {
            #pragma unroll
            for (int q = 0; q < 4; q++) {
                acc[q].x += __shfl_xor(acc[q].x, msk, 64);
                acc[q].y += __shfl_xor(acc[q].y, msk, 64);
                acc[q].z += __shfl_xor(acc[q].z, msk, 64);
                acc[q].w += __shfl_xor(acc[q].w, msk, 64);
            }
        }
        if (g == 0) {
            float sc = rsqrtf((float)(deg < 1 ? 1 : deg));
            #pragma unroll
            for (int q = 0; q < 4; q++) {
                float4 b = *(const float4*)&bias[c + q * 4];
                float4 r = make_float4(acc[q].x * sc + b.x, acc[q].y * sc + b.y,
                                       acc[q].z * sc + b.z, acc[q].w * sc + b.w);
                *(float4*)&out_rst[(size_t)n * OUTF + c + q * 4] = r;
            }
        }
    } else {
        // rare fallback (deg > 64): full-wave per edge, e spilled to e_tmp
        int c = lane * 2;
        float2 hd = *(const float2*)&h[(size_t)n * OUTF + c];
        float tx = tanhf(hd.x), ty = tanhf(hd.y);
        float2 acc = make_float2(0.f, 0.f);
        float runmax = -INFINITY;
        for (int base = 0; base < deg; base += 64) {
            int cnt = min(64, deg - base);
            int s = 0;
            if (lane < cnt) s = src[ebd[off + base + lane]];
            for (int j = 0; j < cnt; j++) {
                int sj = __shfl(s, j, 64);
                float2 hs = *(const float2*)&h[(size_t)sj * OUTF + c];
                acc.x += hs.x; acc.y += hs.y;
                float p = hs.x * tx + hs.y * ty;
                #pragma unroll
                for (int m = 1; m < 64; m <<= 1) p += __shfl_xor(p, m, 64);
                float e = p > 0.f ? p : NEG_SLOPE * p;
                runmax = fmaxf(runmax, e);
                if (lane == 0) e_tmp[off + base + j] = e;
            }
        }
        __threadfence();
        float lsum = 0.f;
        for (int j = lane; j < deg; j += 64) {
            float v = expf(e_tmp[off + j] - runmax);
            e_tmp[off + j] = v;
            lsum += v;
        }
        #pragma unroll
        for (int m = 1; m < 64; m <<= 1) lsum += __shfl_xor(lsum, m, 64);
        float inv = 1.f / lsum;
        __threadfence();
        for (int j = lane; j < deg; j += 64)
            out_es[ebd[off + j]] = e_tmp[off + j] * inv;

        float sc = rsqrtf((float)deg);
        float2 b2 = *(const float2*)&bias[c];
        float2 r = make_float2(acc.x * sc + b2.x, acc.y * sc + b2.y);
        *(float2*)&out_rst[(size_t)n * OUTF + c] = r;
    }
}

// ---------------- launch ----------------
extern "C" void kernel_launch(void* const* d_in, const int* in_sizes, int n_in,
                              void* d_out, int out_size, void* d_ws, size_t ws_size,
                              hipStream_t stream) {
    const float* feat = (const float*)d_in[0];
    const float* W    = (const float*)d_in[1];
    const float* bias = (const float*)d_in[2];
    const int*   src  = (const int*)d_in[3];
    const int*   dst  = (const int*)d_in[4];

    float* out_rst = (float*)d_out;
    float* out_es  = (float*)d_out + (size_t)NNODES * OUTF;

    char* ws = (char*)d_ws;
    size_t o = 0;
    auto alloc = [&](size_t bytes) { void* p = ws + o; o += (bytes + 255) & ~(size_t)255; return p; };
    int*   cnt_out = (int*)alloc(NNODES * 4);
    int*   cnt_in  = (int*)alloc(NNODES * 4);
    int*   fill    = (int*)alloc(NNODES * 4);
    int*   offs    = (int*)alloc((NNODES + 1) * 4);
    int*   bsums   = (int*)alloc(64 * 4);
    int*   ebd     = (int*)alloc(NEDGES * 4);
    float* e_tmp   = (float*)alloc(NEDGES * 4);
    float* h       = (float*)alloc((size_t)NNODES * OUTF * 4);
    (void)o; (void)ws_size; (void)in_sizes; (void)n_in; (void)out_size;

    const int zints = (int)(3 * (((size_t)NNODES * 4 + 255) & ~(size_t)255) / 4);
    kzero<<<(zints + 255) / 256, 256, 0, stream>>>((int*)d_ws, zints);

    kdegrees<<<(NEDGES + 255) / 256, 256, 0, stream>>>(src, dst, cnt_out, cnt_in, NEDGES);

    const int nb = (NNODES + 1023) / 1024;   // 49
    kblocksum<<<nb, 1024, 0, stream>>>(cnt_in, bsums, NNODES);
    kscanfull<<<nb, 1024, 0, stream>>>(cnt_in, bsums, offs, NNODES, nb);

    kbucket<<<(NEDGES + 255) / 256, 256, 0, stream>>>(dst, offs, fill, ebd, NEDGES);

    kgemm<<<(NNODES + BM - 1) / BM, 256, 0, stream>>>(feat, W, cnt_out, h, NNODES);

    kaggregate<<<(NNODES + 3) / 4, 256, 0, stream>>>(h, src, ebd, offs, cnt_in, bias,
                                                     e_tmp, out_rst, out_es, NNODES);
}